// Round 8
// baseline (2438.300 us; speedup 1.0000x reference)
//
#include <hip/hip_runtime.h>
#include <math.h>

#define T_ 200
#define WROW 284                       // LDS row stride (256 + swizzle room)
#define SMEM_FLOATS (128 * WROW + 16 * WROW)
#define SMEM_BYTES (SMEM_FLOATS * 4)   // 163,584 <= 163,840 (160 KiB)

typedef float f32x2 __attribute__((ext_vector_type(2)));

__device__ __forceinline__ float fsig(float x) {
  return 1.f / (1.f + __expf(-x));
}
__device__ __forceinline__ float ftanh(float x) {
  return 1.f - 2.f / (__expf(2.f * x) + 1.f);   // exact at +-inf, no NaN
}
// DPP cross-lane adds on the VALU pipe (no LDS/lgkm): quad_perm xor1/xor2.
__device__ __forceinline__ float dpp_xor1(float x) {
  return __int_as_float(__builtin_amdgcn_update_dpp(
      0, __float_as_int(x), 0xB1, 0xF, 0xF, true));   // [1,0,3,2]
}
__device__ __forceinline__ float dpp_xor2(float x) {
  return __int_as_float(__builtin_amdgcn_update_dpp(
      0, __float_as_int(x), 0x4E, 0xF, 0xF, true));   // [2,3,0,1]
}

// ---------------- xg tile body (r13-proven gather version) as a device
// function over LDS slices; used by the standalone prologue kernel (256t)
// and the fused kernel's xg role (512t = two 256t halves, paired n0 tiles).
__device__ __forceinline__ void xg_tile(
    float* As, float* Bs,                  // As[32][140], Bs[32][132] slices
    int tid,                               // 0..255 within the half
    int t_blk, int m0, int n0,
    const int* __restrict__ bin, const int* __restrict__ bfe,
    const float* __restrict__ ctab, const float* __restrict__ ftab,
    const float* __restrict__ wih, const float* __restrict__ bias,
    float* __restrict__ xgslot) {
  const int mm = tid & 15;
  const int nn = tid >> 4;
  const int ra = tid & 127;            // staging row (A: m, B: n)
  const int ka = (tid >> 7) << 4;      // k-offset 0 or 16

  const int bcol = (m0 + ra) & 255;
  const float* cr = ctab + ((size_t)bin[bcol * T_ + t_blk] << 8);
  const float* fr = ftab + ((size_t)bfe[bcol * T_ + t_blk] << 8);
  const float* br = wih + (size_t)(n0 + ra) * 256;
  const int cwa = ra + ((ra >> 5) << 2);   // swizzled A col for m=ra

  f32x2 acc[8][4];                      // [i][j-pair]
  #pragma unroll
  for (int i = 0; i < 8; ++i)
    #pragma unroll
    for (int j = 0; j < 4; ++j) acc[i][j] = (f32x2){0.f, 0.f};

  const int am0 = mm * 8 + ((mm >> 2) << 2);   // swizzled base col for A reads
  const int bn0 = nn * 8;

  for (int ks = 0; ks < 256; ks += 32) {
    float4 c4[4], f4v[4], b4[4];
    #pragma unroll
    for (int w = 0; w < 4; ++w) {
      c4[w]  = *(const float4*)(cr + ks + ka + w * 4);
      f4v[w] = *(const float4*)(fr + ks + ka + w * 4);
      b4[w]  = *(const float4*)(br + ks + ka + w * 4);
    }
    __syncthreads();   // previous iteration's consumers done (block-wide)
    #pragma unroll
    for (int w = 0; w < 4; ++w) {
      int kk = ka + w * 4;
      As[(kk + 0) * 140 + cwa] = c4[w].x * f4v[w].x;
      As[(kk + 1) * 140 + cwa] = c4[w].y * f4v[w].y;
      As[(kk + 2) * 140 + cwa] = c4[w].z * f4v[w].z;
      As[(kk + 3) * 140 + cwa] = c4[w].w * f4v[w].w;
      Bs[(kk + 0) * 132 + ra] = b4[w].x;
      Bs[(kk + 1) * 132 + ra] = b4[w].y;
      Bs[(kk + 2) * 132 + ra] = b4[w].z;
      Bs[(kk + 3) * 132 + ra] = b4[w].w;
    }
    __syncthreads();
    #pragma unroll 4
    for (int k = 0; k < 32; ++k) {
      float4 a0 = *(const float4*)&As[k * 140 + am0];
      float4 a1 = *(const float4*)&As[k * 140 + am0 + 4];
      float4 b0 = *(const float4*)&Bs[k * 132 + bn0];
      float4 b1 = *(const float4*)&Bs[k * 132 + bn0 + 4];
      float am[8] = {a0.x, a0.y, a0.z, a0.w, a1.x, a1.y, a1.z, a1.w};
      f32x2 bp[4] = {{b0.x, b0.y}, {b0.z, b0.w}, {b1.x, b1.y}, {b1.z, b1.w}};
      #pragma unroll
      for (int i = 0; i < 8; ++i) {
        f32x2 av = {am[i], am[i]};
        #pragma unroll
        for (int j = 0; j < 4; ++j)
          acc[i][j] = __builtin_elementwise_fma(av, bp[j], acc[i][j]);
      }
    }
  }

  float4 bv0 = *(const float4*)(bias + n0 + bn0);
  float4 bv1 = *(const float4*)(bias + n0 + bn0 + 4);
  #pragma unroll
  for (int i = 0; i < 8; ++i) {
    int row = m0 + mm * 8 + i;
    float4 o0, o1;
    o0.x = acc[i][0].x + bv0.x; o0.y = acc[i][0].y + bv0.y;
    o0.z = acc[i][1].x + bv0.z; o0.w = acc[i][1].y + bv0.w;
    o1.x = acc[i][2].x + bv1.x; o1.y = acc[i][2].y + bv1.y;
    o1.z = acc[i][3].x + bv1.z; o1.w = acc[i][3].y + bv1.w;
    *(float4*)(xgslot + (size_t)row * 1024 + n0 + bn0) = o0;
    *(float4*)(xgslot + (size_t)row * 1024 + n0 + bn0 + 4) = o1;
  }
}

// ---------------- standalone xg (prologue chunk 0): r13-proven shape.
__global__ __launch_bounds__(256) void xg_gemm(
    const int* __restrict__ bin, const int* __restrict__ bfe,
    const int* __restrict__ blen,
    const float* __restrict__ ctab, const float* __restrict__ ftab,
    const float* __restrict__ wihf, const float* __restrict__ biasf,
    const float* __restrict__ wihb, const float* __restrict__ biasb,
    float* __restrict__ xgf, float* __restrict__ xgb, int cc) {
  const int dir = blockIdx.z;
  const int m0 = blockIdx.x * 128;
  const int rloc = m0 >> 8;
  const int t_blk = dir ? (199 - cc - rloc) : (cc + rloc);
  if (t_blk >= blen[m0 & 255]) return;   // fully masked tile (sorted lengths)
  __shared__ float As[32 * 140];
  __shared__ float Bs[32 * 132];
  xg_tile(As, Bs, threadIdx.x, t_blk, m0, blockIdx.y * 128, bin, bfe, ctab,
          ftab, dir ? wihb : wihf, dir ? biasb : biasf, dir ? xgb : xgf);
}

// ---------------- fused kernel (r15): blocks [0,256) = lstm chunk c (r14
// body + per-group step-range trimming); blocks [256, 256+nxg) = xg for
// chunk c+1 (two n0-paired tiles per 512-thread block). xg blocks backfill
// CUs freed by early-exiting lstm groups; they never wait on lstm (no
// deadlock possible). Groups are independent: bar, hst regions per (dir,bc).
__global__ __launch_bounds__(512, 1) void lstm_fused(
    const float* __restrict__ xgfr, const float* __restrict__ xgbr,
    const float* __restrict__ whf, const float* __restrict__ whb,
    const int* __restrict__ blen,
    float* __restrict__ hst, float* __restrict__ cst,
    float* __restrict__ hout, unsigned* __restrict__ bar,
    int s0, int nsteps, int Cn,
    const int* __restrict__ bin, const int* __restrict__ bfe,
    const float* __restrict__ ctab, const float* __restrict__ ftab,
    const float* __restrict__ wihf, const float* __restrict__ biasf,
    const float* __restrict__ wihb, const float* __restrict__ biasb,
    float* __restrict__ xgfw, float* __restrict__ xgbw, int ccn) {
  extern __shared__ float smem[];
  const int bid = blockIdx.x;

  if (bid >= 256) {   // ---------------- xg role (chunk c+1)
    const int xid = bid - 256;
    const int x = xid % (2 * Cn);
    const int rest = xid / (2 * Cn);
    const int pair = rest & 3;
    const int dirx = rest >> 2;
    const int m0 = x * 128;
    const int rloc = x >> 1;
    const int t_blk = dirx ? (199 - ccn - rloc) : (ccn + rloc);
    if (t_blk >= blen[(x & 1) * 128]) return;   // uniform across block
    const int half = threadIdx.x >> 8;          // two 256t halves
    float* As = smem + half * 8704;
    float* Bs = As + 32 * 140;
    xg_tile(As, Bs, threadIdx.x & 255, t_blk, m0, (pair * 2 + half) * 128,
            bin, bfe, ctab, ftab, dirx ? wihb : wihf, dirx ? biasb : biasf,
            dirx ? xgbw : xgfw);
    return;
  }

  // ---------------- lstm role: r14 body + step-range trimming
  float* wlds = smem;                 // [128][WROW]
  float* hlds = smem + 128 * WROW;    // [16][WROW]

  const int bc = bid & 15, js = (bid >> 4) & 7, dir = bid >> 7;
  const int tid = threadIdx.x;
  const int ks = tid & 7;
  const int bg = (tid >> 3) & 3;
  const int rg = tid >> 5;            // 0..15
  const int grp = dir * 16 + bc;
  const float* wh = dir ? whb : whf;
  const float* xgp = dir ? xgbr : xgfr;

  // active absolute step range for this group (sorted lengths)
  const int maxlen = blen[bc * 16];
  const int first_s = dir ? (200 - maxlen) : 0;
  const int last_s  = dir ? 200 : maxlen;
  if (s0 >= last_s || s0 + nsteps <= first_s) return;   // uniform per block
  const int r_lo = (first_s > s0) ? (first_s - s0) : 0;
  const int r_hi = (last_s - s0 < nsteps) ? (last_s - s0) : nsteps;

  // ---- stage W once per chunk (permuted rows: prow = rgs*8 + g*2 + u)
  #pragma unroll
  for (int i = 0; i < 16; ++i) {
    int f = tid + i * 512;            // float4 id 0..8191
    int prow = f >> 6;
    int k = (f & 63) << 2;
    int g = (prow >> 1) & 3, u = prow & 1, rgs = prow >> 3;
    int jg = js * 32 + rgs * 2 + u;
    float4 v = *(const float4*)(wh + ((size_t)(g * 256 + jg)) * 256 + k);
    *(float4*)&wlds[prow * WROW + k + ((k >> 5) << 2)] = v;
  }

  const int bl_th = bg * 4 + (ks & 3);      // local batch 0..15
  const int b_th = bc * 16 + bl_th;         // global batch
  const int u_th = ks >> 2;
  const int jth = js * 32 + rg * 2 + u_th;  // this thread's j
  const int cjth = jth + ((jth >> 5) << 2); // swizzled col of jth
  const int len_th = blen[b_th];
  float c0 = cst[((size_t)dir * 256 + b_th) * 256 + jth];

  // ---- prologue xq (first active step): latency hidden under W staging
  float xq[4];
  #pragma unroll
  for (int g = 0; g < 4; ++g)
    xq[g] = xgp[((size_t)r_lo * 256 + b_th) * 1024 + g * 256 + jth];

  float hprev = 0.f;   // h[b_th][jth]; seeded from hlds at first active step

  __syncthreads();   // W staged

  for (int r = r_lo; r < r_hi; ++r) {
    const int s = s0 + r;
    const int tt = dir ? (199 - s) : s;
    const int rslot = s & 1, wslot = 1 - rslot;

    // ---- stage h[16 b][256 k]: 2 agent-scope (sc1) dwordx4 per thread.
    const float* hsrc = hst + (((size_t)(rslot * 2 + dir)) * 256 + bc * 16) * 256;
    {
      const int f0 = tid, f1 = tid + 512;        // float4 ids
      const int b0i = f0 >> 6, k0 = (f0 & 63) << 2;
      const int b1i = f1 >> 6, k1 = (f1 & 63) << 2;
      const float* p0 = hsrc + (b0i << 8) + k0;
      const float* p1 = hsrc + (b1i << 8) + k1;
      float4 v0, v1;
      asm volatile(
          "global_load_dwordx4 %0, %2, off sc1\n\t"
          "global_load_dwordx4 %1, %3, off sc1\n\t"
          "s_waitcnt vmcnt(0)"
          : "=&v"(v0), "=&v"(v1)
          : "v"(p0), "v"(p1)
          : "memory");
      *(float4*)&hlds[b0i * WROW + k0 + ((k0 >> 5) << 2)] = v0;
      *(float4*)&hlds[b1i * WROW + k1 + ((k1 >> 5) << 2)] = v1;
    }
    __syncthreads();

    if (r == r_lo) hprev = hlds[bl_th * WROW + cjth];   // seed (h init or carry)

    // ---- prefetch NEXT step's xq; HBM/L3 latency lands under the GEMM
    float xqn[4];
    const int rn = (r + 1 < r_hi) ? (r + 1) : r;
    #pragma unroll
    for (int g = 0; g < 4; ++g)
      xqn[g] = xgp[((size_t)rn * 256 + b_th) * 1024 + g * 256 + jth];

    // ---- GEMM: packed acc2[i][bb], lo/hi = k-even/odd partial sums
    f32x2 acc2[8][4];
    #pragma unroll
    for (int i = 0; i < 8; ++i)
      #pragma unroll
      for (int bb = 0; bb < 4; ++bb) acc2[i][bb] = (f32x2){0.f, 0.f};

    #pragma unroll
    for (int kq = 0; kq < 8; ++kq) {
      const int col = ks * 36 + kq * 4;
      float4 h4[4];
      #pragma unroll
      for (int bb = 0; bb < 4; ++bb)
        h4[bb] = *(const float4*)&hlds[(bg * 4 + bb) * WROW + col];
      f32x2 hlo[4], hhi[4];
      #pragma unroll
      for (int bb = 0; bb < 4; ++bb) {
        hlo[bb] = (f32x2){h4[bb].x, h4[bb].y};
        hhi[bb] = (f32x2){h4[bb].z, h4[bb].w};
      }
      #pragma unroll
      for (int i = 0; i < 8; ++i) {
        float4 w4 = *(const float4*)&wlds[(rg * 8 + i) * WROW + col];
        f32x2 wlo = (f32x2){w4.x, w4.y};
        f32x2 whi = (f32x2){w4.z, w4.w};
        #pragma unroll
        for (int bb = 0; bb < 4; ++bb) {
          acc2[i][bb] = __builtin_elementwise_fma(wlo, hlo[bb], acc2[i][bb]);
          acc2[i][bb] = __builtin_elementwise_fma(whi, hhi[bb], acc2[i][bb]);
        }
      }
    }

    float acc[8][4];
    #pragma unroll
    for (int i = 0; i < 8; ++i)
      #pragma unroll
      for (int bb = 0; bb < 4; ++bb)
        acc[i][bb] = acc2[i][bb].x + acc2[i][bb].y;

    // ---- butterfly over ks: xor1/xor2 (DPP) route batches, xor4 finishes
    const int bit0 = ks & 1, bit1 = (ks >> 1) & 1;
    float fin[8];
    #pragma unroll
    for (int i = 0; i < 8; ++i) {
      float k0 = bit0 ? acc[i][1] : acc[i][0];
      float s0v = bit0 ? acc[i][0] : acc[i][1];
      float k1 = bit0 ? acc[i][3] : acc[i][2];
      float s1v = bit0 ? acc[i][2] : acc[i][3];
      float r0 = k0 + dpp_xor1(s0v);
      float r1 = k1 + dpp_xor1(s1v);
      float k2 = bit1 ? r1 : r0;
      float s2v = bit1 ? r0 : r1;
      float r2 = k2 + dpp_xor2(s2v);
      fin[i] = r2 + __shfl_xor(r2, 4);
    }

    // ---- cell update (1 cell per thread: batch b_th, hidden jth)
    float gi = fsig((u_th ? fin[1] : fin[0]) + xq[0]);
    float gf = fsig((u_th ? fin[3] : fin[2]) + xq[1]);
    float gg = ftanh((u_th ? fin[5] : fin[4]) + xq[2]);
    float go = fsig((u_th ? fin[7] : fin[6]) + xq[3]);
    float cn = gf * c0 + gi * gg;
    float hn = go * ftanh(cn);
    const bool mk = tt < len_th;
    if (mk) c0 = cn;
    float hsv = mk ? hn : hprev;
    hprev = hsv;
    __hip_atomic_store(
        hst + (((size_t)(wslot * 2 + dir)) * 256 + b_th) * 256 + jth,
        hsv, __ATOMIC_RELAXED, __HIP_MEMORY_SCOPE_AGENT);

    // ---- drain h stores, signal, hout store overlaps the poll.
    // EXACT r7 protocol within active steps — do not restructure.
    asm volatile("s_waitcnt vmcnt(0)" ::: "memory");
    __syncthreads();
    if (tid == 0)
      __hip_atomic_fetch_add(&bar[grp * 32], 1u, __ATOMIC_RELAXED,
                             __HIP_MEMORY_SCOPE_AGENT);
    hout[(((size_t)dir * 200 + tt) * 256 + b_th) * 256 + jth] = mk ? hn : 0.f;
    if (tid == 0) {
      const unsigned tgt = 8u * (unsigned)(s - first_s + 1);
      while (__hip_atomic_load(&bar[grp * 32], __ATOMIC_RELAXED,
                               __HIP_MEMORY_SCOPE_AGENT) < tgt) {}
    }
    __syncthreads();

    #pragma unroll
    for (int g = 0; g < 4; ++g) xq[g] = xqn[g];
  }

  cst[((size_t)dir * 256 + b_th) * 256 + jth] = c0;
}

// ---------------- feats: r11 tile early-exit + r15 zero-guard (hout rows for
// t >= len[b] may now be unwritten; reference has them 0; viterbi never reads
// the corresponding feats, but guard keeps the GEMM well-defined).
__global__ __launch_bounds__(256) void feats_kernel(
    const float* __restrict__ h_out, const float* __restrict__ wtag,
    const float* __restrict__ btag, float* __restrict__ feats,
    const int* __restrict__ blen) {
  const int t = blockIdx.x, bc = blockIdx.y;
  if (t >= blen[bc * 32]) return;   // sorted lengths: tile max is first row
  __shared__ float hcat[32][512];
  const int tid = threadIdx.x;
  const float* hf = h_out + (((size_t)0 * 200 + t) * 256 + bc * 32) * 256;
  const float* hb = h_out + (((size_t)1 * 200 + t) * 256 + bc * 32) * 256;
  const float4 z4 = {0.f, 0.f, 0.f, 0.f};
  for (int i = tid; i < 2048; i += 256) {
    int row = i >> 6, c4 = (i & 63) << 2;
    bool live = t < blen[bc * 32 + row];
    *(float4*)&hcat[row][c4] =
        live ? *(const float4*)(hf + (size_t)row * 256 + c4) : z4;
    *(float4*)&hcat[row][256 + c4] =
        live ? *(const float4*)(hb + (size_t)row * 256 + c4) : z4;
  }
  __syncthreads();
  const int kk = tid & 63;
  const int bg = tid >> 6;
  if (kk < 52) {
    f32x2 acc2[8];
    #pragma unroll
    for (int i = 0; i < 8; ++i) acc2[i] = (f32x2){0.f, 0.f};
    const float* wr = wtag + (size_t)kk * 512;
    for (int jq = 0; jq < 128; ++jq) {
      float4 wv = *(const float4*)(wr + jq * 4);
      f32x2 wlo = (f32x2){wv.x, wv.y};
      f32x2 whi = (f32x2){wv.z, wv.w};
      #pragma unroll
      for (int bi = 0; bi < 8; ++bi) {
        float4 hv = *(const float4*)&hcat[bg * 8 + bi][jq * 4];
        f32x2 hlo = (f32x2){hv.x, hv.y};
        f32x2 hhi = (f32x2){hv.z, hv.w};
        acc2[bi] = __builtin_elementwise_fma(wlo, hlo, acc2[bi]);
        acc2[bi] = __builtin_elementwise_fma(whi, hhi, acc2[bi]);
      }
    }
    float bv = btag[kk];
    #pragma unroll
    for (int bi = 0; bi < 8; ++bi)
      feats[(size_t)(bc * 32 + bg * 8 + bi) * 10400 + t * 52 + kk] =
          acc2[bi].x + acc2[bi].y + bv;
  }
}

// ---------------- Viterbi v4 (r11, proven): one WAVE per batch row.
__global__ __launch_bounds__(64) void viterbi_kernel(
    const float* __restrict__ feats, const float* __restrict__ trans,
    const int* __restrict__ blen, float* __restrict__ out) {
  __shared__ float flds[10400];
  __shared__ float pl[56];
  __shared__ unsigned char bp[199 * 52];

  const int b = blockIdx.x;
  const int lane = threadIdx.x;
  const int kk = (lane < 52) ? lane : 0;
  const float* fb = feats + (size_t)b * 10400;
  const int len = blen[b];

  const int nf4 = (len * 52 + 3) >> 2;   // only the live prefix of feats
  for (int i = lane; i < nf4; i += 64)
    *(float4*)&flds[i * 4] = *(const float4*)(fb + i * 4);

  float trc[52];
  #pragma unroll
  for (int j = 0; j < 52; ++j) trc[j] = trans[j * 52 + kk];
  __syncthreads();

  float part = trans[50 * 52 + kk] + flds[kk];   // START row = 50
  if (lane < 52) pl[lane] = part;

  for (int t = 1; t < len; ++t) {   // all iterations unmasked by construction
    const float ftk = flds[t * 52 + kk];
    float pa[52];
    #pragma unroll
    for (int q = 0; q < 13; ++q) {
      float4 v = *(const float4*)&pl[q * 4];
      pa[q * 4 + 0] = v.x; pa[q * 4 + 1] = v.y;
      pa[q * 4 + 2] = v.z; pa[q * 4 + 3] = v.w;
    }
    float mv0 = -1e30f, mv1 = -1e30f, mv2 = -1e30f, mv3 = -1e30f;
    int mj0 = 0, mj1 = 13, mj2 = 26, mj3 = 39;
    #pragma unroll
    for (int q = 0; q < 13; ++q) {
      float c0v = (pa[q] + trc[q]) + ftk;
      if (c0v > mv0) { mv0 = c0v; mj0 = q; }
      float c1v = (pa[13 + q] + trc[13 + q]) + ftk;
      if (c1v > mv1) { mv1 = c1v; mj1 = 13 + q; }
      float c2v = (pa[26 + q] + trc[26 + q]) + ftk;
      if (c2v > mv2) { mv2 = c2v; mj2 = 26 + q; }
      float c3v = (pa[39 + q] + trc[39 + q]) + ftk;
      if (c3v > mv3) { mv3 = c3v; mj3 = 39 + q; }
    }
    float mv = mv0; int mj = mj0;
    if (mv1 > mv) { mv = mv1; mj = mj1; }
    if (mv2 > mv) { mv = mv2; mj = mj2; }
    if (mv3 > mv) { mv = mv3; mj = mj3; }
    if (lane < 52) {
      bp[(t - 1) * 52 + lane] = (unsigned char)mj;
      part = mv; pl[lane] = mv;
    }
  }

  float fin = (lane < 52) ? (part + trans[lane * 52 + 51]) : -1e30f;
  int bi = lane;
  #pragma unroll
  for (int off = 32; off; off >>= 1) {
    float ov = __shfl_down(fin, off);
    int oi = __shfl_down(bi, off);
    if (ov > fin || (ov == fin && oi < bi)) { fin = ov; bi = oi; }
  }
  if (lane == 0) {
    out[b] = fin;
    float* dec = out + 256 + (size_t)b * 200;
    for (int i = len; i < 200; ++i) dec[i] = 0.f;   // masked tail
    int tag = bi;
    dec[len - 1] = (float)tag;                       // == bi (identity beyond)
    for (int i = len - 2; i >= 0; --i) {
      tag = bp[i * 52 + tag];                        // bp[i] real for i<=len-2
      dec[i] = (float)tag;
    }
  }
}

extern "C" void kernel_launch(void* const* d_in, const int* in_sizes, int n_in,
                              void* d_out, int out_size, void* d_ws, size_t ws_size,
                              hipStream_t stream) {
  const int*   bin  = (const int*)d_in[0];
  const int*   bfe  = (const int*)d_in[1];
  const int*   blen = (const int*)d_in[2];
  const float* ctab = (const float*)d_in[5];
  const float* ftab = (const float*)d_in[6];
  const float* wihf = (const float*)d_in[7];
  const float* whhf = (const float*)d_in[8];
  const float* bf   = (const float*)d_in[9];
  const float* wihb = (const float*)d_in[10];
  const float* whhb = (const float*)d_in[11];
  const float* bb   = (const float*)d_in[12];
  const float* wtag = (const float*)d_in[13];
  const float* btag = (const float*)d_in[14];
  const float* trn  = (const float*)d_in[15];

  (void)hipFuncSetAttribute(reinterpret_cast<const void*>(lstm_fused),
                            hipFuncAttributeMaxDynamicSharedMemorySize,
                            SMEM_BYTES);

  const size_t FIXED_F = 29271040;      // hst+cst+hout+fts+bar
  size_t ws_f = ws_size / sizeof(float);
  int C = 1;
  const int cands[10] = {50, 40, 25, 20, 10, 8, 5, 4, 2, 1};
  for (int u = 0; u < 10; ++u) {
    if (FIXED_F + (size_t)4 * cands[u] * 262144 <= ws_f) { C = cands[u]; break; }
  }

  float* ws   = (float*)d_ws;
  float* xg0f = ws;                           // double-buffered xg
  float* xg0b = xg0f + (size_t)C * 262144;
  float* xg1f = xg0b + (size_t)C * 262144;
  float* xg1b = xg1f + (size_t)C * 262144;
  float* hst  = xg1b + (size_t)C * 262144;    // 2 slots x 2 dir x 256 x 256
  float* cst  = hst + 262144;
  float* hout = cst + 131072;                 // 2 dir x 200 x 256 x 256
  float* fts  = hout + 26214400;
  unsigned* bar = (unsigned*)(fts + 2662400); // 32 groups x stride 32
  float* out  = (float*)d_out;

  hipMemsetAsync(hst, 0, (size_t)(262144 + 131072) * sizeof(float), stream);
  hipMemsetAsync(bar, 0, 1024 * sizeof(unsigned), stream);

  const int nchunks = 200 / C;
  // prologue: xg chunk 0 -> buffer 0
  xg_gemm<<<dim3(2 * C, 8, 2), 256, 0, stream>>>(
      bin, bfe, blen, ctab, ftab, wihf, bf, wihb, bb, xg0f, xg0b, 0);

  for (int c = 0; c < nchunks; ++c) {
    const int nxg = (c + 1 < nchunks) ? 16 * C : 0;   // paired-tile xg blocks
    float* rf = (c & 1) ? xg1f : xg0f;
    float* rb = (c & 1) ? xg1b : xg0b;
    float* wf = (c & 1) ? xg0f : xg1f;
    float* wb = (c & 1) ? xg0b : xg1b;
    lstm_fused<<<dim3(256 + nxg), 512, SMEM_BYTES, stream>>>(
        rf, rb, whhf, whhb, blen, hst, cst, hout, bar, c * C, C, C,
        bin, bfe, ctab, ftab, wihf, bf, wihb, bb, wf, wb, (c + 1) * C);
  }
  feats_kernel<<<dim3(200, 8), 256, 0, stream>>>(hout, wtag, btag, fts, blen);
  viterbi_kernel<<<256, 64, 0, stream>>>(fts, trn, blen, out);
}

// Round 9
// 1908.028 us; speedup vs baseline: 1.2779x; 1.2779x over previous
//
#include <hip/hip_runtime.h>
#include <math.h>

#define T_ 200
#define WROW 284                       // LDS row stride (256 + swizzle room)
#define SMEM_FLOATS (128 * WROW + 16 * WROW)
#define SMEM_BYTES (SMEM_FLOATS * 4)   // 163,584 <= 163,840 (160 KiB)

typedef float f32x2 __attribute__((ext_vector_type(2)));

__device__ __forceinline__ float fsig(float x) {
  return 1.f / (1.f + __expf(-x));
}
__device__ __forceinline__ float ftanh(float x) {
  return 1.f - 2.f / (__expf(2.f * x) + 1.f);   // exact at +-inf, no NaN
}
// DPP cross-lane adds on the VALU pipe (no LDS/lgkm): quad_perm xor1/xor2.
__device__ __forceinline__ float dpp_xor1(float x) {
  return __int_as_float(__builtin_amdgcn_update_dpp(
      0, __float_as_int(x), 0xB1, 0xF, 0xF, true));   // [1,0,3,2]
}
__device__ __forceinline__ float dpp_xor2(float x) {
  return __int_as_float(__builtin_amdgcn_update_dpp(
      0, __float_as_int(x), 0x4E, 0xF, 0xF, true));   // [2,3,0,1]
}

// ---------------- emb precompute (r14, proven): emb[t][b][e] = ctab*ftab.
__global__ __launch_bounds__(256) void emb_kernel(
    const int* __restrict__ bin, const int* __restrict__ bfe,
    const int* __restrict__ blen,
    const float* __restrict__ ctab, const float* __restrict__ ftab,
    float* __restrict__ emb) {
  const int t = blockIdx.x;
  const int bc8 = blockIdx.y;            // 8 groups of 32 batches
  if (t >= blen[(bc8 >= 4) ? 128 : 0]) return;
  const int tid = threadIdx.x;
  for (int i = tid; i < 2048; i += 256) {   // 32 rows x 64 float4
    int row = i >> 6;
    int c4 = (i & 63) << 2;
    int b = bc8 * 32 + row;
    const float* cr = ctab + ((size_t)bin[b * T_ + t] << 8);
    const float* fr = ftab + ((size_t)bfe[b * T_ + t] << 8);
    float4 cv = *(const float4*)(cr + c4);
    float4 fv = *(const float4*)(fr + c4);
    float4 o;
    o.x = cv.x * fv.x; o.y = cv.y * fv.y;
    o.z = cv.z * fv.z; o.w = cv.w * fv.w;
    *(float4*)(emb + ((size_t)t * 256 + b) * 256 + c4) = o;
  }
}

// ---------------- xg GEMM v5 (r14, proven): fused directions, A staged
// linearly from precomputed emb.
__global__ __launch_bounds__(256) void xg_gemm(
    const int* __restrict__ blen, const float* __restrict__ emb,
    const float* __restrict__ wihf, const float* __restrict__ biasf,
    const float* __restrict__ wihb, const float* __restrict__ biasb,
    float* __restrict__ xgf, float* __restrict__ xgb, int cc) {
  const int dir = blockIdx.z;
  const int m0 = blockIdx.x * 128;
  const int rloc = m0 >> 8;
  const int t_blk = dir ? (199 - cc - rloc) : (cc + rloc);
  if (t_blk >= blen[m0 & 255]) return;   // fully masked tile (sorted lengths)

  const float* wih  = dir ? wihb : wihf;
  const float* bias = dir ? biasb : biasf;
  float* xgslot     = dir ? xgb : xgf;

  __shared__ float As[32][140];   // [k][m swizzled]
  __shared__ float Bs[32][132];   // [k][n]
  const int tid = threadIdx.x;
  const int n0 = blockIdx.y * 128;
  const int mm = tid & 15;
  const int nn = tid >> 4;

  const int ra = tid & 127;            // staging row (A: m, B: n)
  const int ka = (tid >> 7) << 4;      // k-offset 0 or 16

  const int bcol = (m0 + ra) & 255;
  const float* cr = emb + ((size_t)t_blk * 256 + bcol) * 256;
  const float* br = wih + (size_t)(n0 + ra) * 256;
  const int cwa = ra + ((ra >> 5) << 2);   // swizzled A col for m=ra

  f32x2 acc[8][4];                      // [i][j-pair]
  #pragma unroll
  for (int i = 0; i < 8; ++i)
    #pragma unroll
    for (int j = 0; j < 4; ++j) acc[i][j] = (f32x2){0.f, 0.f};

  const int am0 = mm * 8 + ((mm >> 2) << 2);   // swizzled base col for A reads
  const int bn0 = nn * 8;

  for (int ks = 0; ks < 256; ks += 32) {
    float4 c4[4], b4[4];
    #pragma unroll
    for (int w = 0; w < 4; ++w) {
      c4[w] = *(const float4*)(cr + ks + ka + w * 4);
      b4[w] = *(const float4*)(br + ks + ka + w * 4);
    }
    __syncthreads();   // previous iteration's consumers done
    #pragma unroll
    for (int w = 0; w < 4; ++w) {
      int kk = ka + w * 4;
      As[kk + 0][cwa] = c4[w].x;
      As[kk + 1][cwa] = c4[w].y;
      As[kk + 2][cwa] = c4[w].z;
      As[kk + 3][cwa] = c4[w].w;
      Bs[kk + 0][ra] = b4[w].x;
      Bs[kk + 1][ra] = b4[w].y;
      Bs[kk + 2][ra] = b4[w].z;
      Bs[kk + 3][ra] = b4[w].w;
    }
    __syncthreads();
    #pragma unroll 4
    for (int k = 0; k < 32; ++k) {
      float4 a0 = *(const float4*)&As[k][am0];
      float4 a1 = *(const float4*)&As[k][am0 + 4];
      float4 b0 = *(const float4*)&Bs[k][bn0];
      float4 b1 = *(const float4*)&Bs[k][bn0 + 4];
      float am[8] = {a0.x, a0.y, a0.z, a0.w, a1.x, a1.y, a1.z, a1.w};
      f32x2 bp[4] = {{b0.x, b0.y}, {b0.z, b0.w}, {b1.x, b1.y}, {b1.z, b1.w}};
      #pragma unroll
      for (int i = 0; i < 8; ++i) {
        f32x2 av = {am[i], am[i]};
        #pragma unroll
        for (int j = 0; j < 4; ++j)
          acc[i][j] = __builtin_elementwise_fma(av, bp[j], acc[i][j]);
      }
    }
  }

  float4 bv0 = *(const float4*)(bias + n0 + bn0);
  float4 bv1 = *(const float4*)(bias + n0 + bn0 + 4);
  #pragma unroll
  for (int i = 0; i < 8; ++i) {
    int row = m0 + mm * 8 + i;
    float4 o0, o1;
    o0.x = acc[i][0].x + bv0.x; o0.y = acc[i][0].y + bv0.y;
    o0.z = acc[i][1].x + bv0.z; o0.w = acc[i][1].y + bv0.w;
    o1.x = acc[i][2].x + bv1.x; o1.y = acc[i][2].y + bv1.y;
    o1.z = acc[i][3].x + bv1.z; o1.w = acc[i][3].y + bv1.w;
    *(float4*)(xgslot + (size_t)row * 1024 + n0 + bn0) = o0;
    *(float4*)(xgslot + (size_t)row * 1024 + n0 + bn0 + 4) = o1;
  }
}

// ---------------- persistent LSTM chunk: r14-proven body (r7 protocol, r9
// xq-prefetch, r10 pk-FMA, hprev register) + r16 per-group step trimming
// (validated inside r15's passing run): masked groups exit/skip their dead
// steps instead of executing them, removing their xq/hout/h-exchange traffic
// from the chip while active groups run. Protocol within active steps is
// EXACT r7. bar counts active steps per group: tgt = 8*(s - first_s + 1).
// NO xg fusion (r15: co-resident streaming work doubles exchange latency).
__global__ __launch_bounds__(512, 1) void lstm_chunk(
    const float* __restrict__ xgf, const float* __restrict__ xgb,
    const float* __restrict__ whf, const float* __restrict__ whb,
    const int* __restrict__ blen,
    float* __restrict__ hst, float* __restrict__ cst,
    float* __restrict__ hout, unsigned* __restrict__ bar,
    int s0, int nsteps) {
  extern __shared__ float smem[];
  float* wlds = smem;                 // [128][WROW]
  float* hlds = smem + 128 * WROW;    // [16][WROW]

  const int bc = blockIdx.x, js = blockIdx.y, dir = blockIdx.z;
  const int tid = threadIdx.x;
  const int ks = tid & 7;
  const int bg = (tid >> 3) & 3;
  const int rg = tid >> 5;            // 0..15
  const int grp = dir * 16 + bc;
  const float* wh = dir ? whb : whf;
  const float* xgp = dir ? xgb : xgf;

  // active absolute step range for this group (sorted lengths)
  const int maxlen = blen[bc * 16];
  const int first_s = dir ? (200 - maxlen) : 0;
  const int last_s  = dir ? 200 : maxlen;
  if (s0 >= last_s || s0 + nsteps <= first_s) return;   // uniform per block
  const int r_lo = (first_s > s0) ? (first_s - s0) : 0;
  const int r_hi = (last_s - s0 < nsteps) ? (last_s - s0) : nsteps;

  // ---- stage W once per chunk (permuted rows: prow = rgs*8 + g*2 + u)
  #pragma unroll
  for (int i = 0; i < 16; ++i) {
    int f = tid + i * 512;            // float4 id 0..8191
    int prow = f >> 6;
    int k = (f & 63) << 2;
    int g = (prow >> 1) & 3, u = prow & 1, rgs = prow >> 3;
    int jg = js * 32 + rgs * 2 + u;
    float4 v = *(const float4*)(wh + ((size_t)(g * 256 + jg)) * 256 + k);
    *(float4*)&wlds[prow * WROW + k + ((k >> 5) << 2)] = v;
  }

  const int bl_th = bg * 4 + (ks & 3);      // local batch 0..15
  const int b_th = bc * 16 + bl_th;         // global batch
  const int u_th = ks >> 2;
  const int jth = js * 32 + rg * 2 + u_th;  // this thread's j
  const int cjth = jth + ((jth >> 5) << 2); // swizzled col of jth
  const int len_th = blen[b_th];
  float c0 = cst[((size_t)dir * 256 + b_th) * 256 + jth];

  // ---- prologue xq (first active step): latency hidden under W staging
  float xq[4];
  #pragma unroll
  for (int g = 0; g < 4; ++g)
    xq[g] = xgp[((size_t)r_lo * 256 + b_th) * 1024 + g * 256 + jth];

  float hprev = 0.f;   // h[b_th][jth]; seeded from hlds at first active step

  __syncthreads();   // W staged

  for (int r = r_lo; r < r_hi; ++r) {
    const int s = s0 + r;
    const int tt = dir ? (199 - s) : s;
    const int rslot = s & 1, wslot = 1 - rslot;

    // ---- stage h[16 b][256 k]: 2 agent-scope (sc1) dwordx4 per thread.
    const float* hsrc = hst + (((size_t)(rslot * 2 + dir)) * 256 + bc * 16) * 256;
    {
      const int f0 = tid, f1 = tid + 512;        // float4 ids
      const int b0i = f0 >> 6, k0 = (f0 & 63) << 2;
      const int b1i = f1 >> 6, k1 = (f1 & 63) << 2;
      const float* p0 = hsrc + (b0i << 8) + k0;
      const float* p1 = hsrc + (b1i << 8) + k1;
      float4 v0, v1;
      asm volatile(
          "global_load_dwordx4 %0, %2, off sc1\n\t"
          "global_load_dwordx4 %1, %3, off sc1\n\t"
          "s_waitcnt vmcnt(0)"
          : "=&v"(v0), "=&v"(v1)
          : "v"(p0), "v"(p1)
          : "memory");
      *(float4*)&hlds[b0i * WROW + k0 + ((k0 >> 5) << 2)] = v0;
      *(float4*)&hlds[b1i * WROW + k1 + ((k1 >> 5) << 2)] = v1;
    }
    __syncthreads();

    if (r == r_lo) hprev = hlds[bl_th * WROW + cjth];   // seed (init or carry)

    // ---- prefetch NEXT step's xq; HBM/L3 latency lands under the GEMM
    float xqn[4];
    const int rn = (r + 1 < r_hi) ? (r + 1) : r;
    #pragma unroll
    for (int g = 0; g < 4; ++g)
      xqn[g] = xgp[((size_t)rn * 256 + b_th) * 1024 + g * 256 + jth];

    // ---- GEMM: packed acc2[i][bb], lo/hi = k-even/odd partial sums
    f32x2 acc2[8][4];
    #pragma unroll
    for (int i = 0; i < 8; ++i)
      #pragma unroll
      for (int bb = 0; bb < 4; ++bb) acc2[i][bb] = (f32x2){0.f, 0.f};

    #pragma unroll
    for (int kq = 0; kq < 8; ++kq) {
      const int col = ks * 36 + kq * 4;
      float4 h4[4];
      #pragma unroll
      for (int bb = 0; bb < 4; ++bb)
        h4[bb] = *(const float4*)&hlds[(bg * 4 + bb) * WROW + col];
      f32x2 hlo[4], hhi[4];
      #pragma unroll
      for (int bb = 0; bb < 4; ++bb) {
        hlo[bb] = (f32x2){h4[bb].x, h4[bb].y};
        hhi[bb] = (f32x2){h4[bb].z, h4[bb].w};
      }
      #pragma unroll
      for (int i = 0; i < 8; ++i) {
        float4 w4 = *(const float4*)&wlds[(rg * 8 + i) * WROW + col];
        f32x2 wlo = (f32x2){w4.x, w4.y};
        f32x2 whi = (f32x2){w4.z, w4.w};
        #pragma unroll
        for (int bb = 0; bb < 4; ++bb) {
          acc2[i][bb] = __builtin_elementwise_fma(wlo, hlo[bb], acc2[i][bb]);
          acc2[i][bb] = __builtin_elementwise_fma(whi, hhi[bb], acc2[i][bb]);
        }
      }
    }

    float acc[8][4];
    #pragma unroll
    for (int i = 0; i < 8; ++i)
      #pragma unroll
      for (int bb = 0; bb < 4; ++bb)
        acc[i][bb] = acc2[i][bb].x + acc2[i][bb].y;

    // ---- butterfly over ks: xor1/xor2 (DPP) route batches, xor4 finishes
    const int bit0 = ks & 1, bit1 = (ks >> 1) & 1;
    float fin[8];
    #pragma unroll
    for (int i = 0; i < 8; ++i) {
      float k0 = bit0 ? acc[i][1] : acc[i][0];
      float s0v = bit0 ? acc[i][0] : acc[i][1];
      float k1 = bit0 ? acc[i][3] : acc[i][2];
      float s1v = bit0 ? acc[i][2] : acc[i][3];
      float r0 = k0 + dpp_xor1(s0v);
      float r1 = k1 + dpp_xor1(s1v);
      float k2 = bit1 ? r1 : r0;
      float s2v = bit1 ? r0 : r1;
      float r2 = k2 + dpp_xor2(s2v);
      fin[i] = r2 + __shfl_xor(r2, 4);
    }

    // ---- cell update (1 cell per thread: batch b_th, hidden jth)
    float gi = fsig((u_th ? fin[1] : fin[0]) + xq[0]);
    float gf = fsig((u_th ? fin[3] : fin[2]) + xq[1]);
    float gg = ftanh((u_th ? fin[5] : fin[4]) + xq[2]);
    float go = fsig((u_th ? fin[7] : fin[6]) + xq[3]);
    float cn = gf * c0 + gi * gg;
    float hn = go * ftanh(cn);
    const bool mk = tt < len_th;
    if (mk) c0 = cn;
    float hsv = mk ? hn : hprev;
    hprev = hsv;
    __hip_atomic_store(
        hst + (((size_t)(wslot * 2 + dir)) * 256 + b_th) * 256 + jth,
        hsv, __ATOMIC_RELAXED, __HIP_MEMORY_SCOPE_AGENT);

    // ---- drain h stores, signal, hout store overlaps the poll.
    // EXACT r7 protocol within active steps — do not restructure.
    asm volatile("s_waitcnt vmcnt(0)" ::: "memory");
    __syncthreads();
    if (tid == 0)
      __hip_atomic_fetch_add(&bar[grp * 32], 1u, __ATOMIC_RELAXED,
                             __HIP_MEMORY_SCOPE_AGENT);
    hout[(((size_t)dir * 200 + tt) * 256 + b_th) * 256 + jth] = mk ? hn : 0.f;
    if (tid == 0) {
      const unsigned tgt = 8u * (unsigned)(s - first_s + 1);
      while (__hip_atomic_load(&bar[grp * 32], __ATOMIC_RELAXED,
                               __HIP_MEMORY_SCOPE_AGENT) < tgt) {}
    }
    __syncthreads();

    #pragma unroll
    for (int g = 0; g < 4; ++g) xq[g] = xqn[g];
  }

  cst[((size_t)dir * 256 + b_th) * 256 + jth] = c0;
}

// ---------------- feats: r11 tile early-exit + r15-validated zero-guard
// (trimmed groups leave hout rows for t >= len[b] unwritten; reference
// value is 0 there; viterbi never reads those feats anyway).
__global__ __launch_bounds__(256) void feats_kernel(
    const float* __restrict__ h_out, const float* __restrict__ wtag,
    const float* __restrict__ btag, float* __restrict__ feats,
    const int* __restrict__ blen) {
  const int t = blockIdx.x, bc = blockIdx.y;
  if (t >= blen[bc * 32]) return;   // sorted lengths: tile max is first row
  __shared__ float hcat[32][512];
  const int tid = threadIdx.x;
  const float* hf = h_out + (((size_t)0 * 200 + t) * 256 + bc * 32) * 256;
  const float* hb = h_out + (((size_t)1 * 200 + t) * 256 + bc * 32) * 256;
  const float4 z4 = {0.f, 0.f, 0.f, 0.f};
  for (int i = tid; i < 2048; i += 256) {
    int row = i >> 6, c4 = (i & 63) << 2;
    bool live = t < blen[bc * 32 + row];
    *(float4*)&hcat[row][c4] =
        live ? *(const float4*)(hf + (size_t)row * 256 + c4) : z4;
    *(float4*)&hcat[row][256 + c4] =
        live ? *(const float4*)(hb + (size_t)row * 256 + c4) : z4;
  }
  __syncthreads();
  const int kk = tid & 63;
  const int bg = tid >> 6;
  if (kk < 52) {
    f32x2 acc2[8];
    #pragma unroll
    for (int i = 0; i < 8; ++i) acc2[i] = (f32x2){0.f, 0.f};
    const float* wr = wtag + (size_t)kk * 512;
    for (int jq = 0; jq < 128; ++jq) {
      float4 wv = *(const float4*)(wr + jq * 4);
      f32x2 wlo = (f32x2){wv.x, wv.y};
      f32x2 whi = (f32x2){wv.z, wv.w};
      #pragma unroll
      for (int bi = 0; bi < 8; ++bi) {
        float4 hv = *(const float4*)&hcat[bg * 8 + bi][jq * 4];
        f32x2 hlo = (f32x2){hv.x, hv.y};
        f32x2 hhi = (f32x2){hv.z, hv.w};
        acc2[bi] = __builtin_elementwise_fma(wlo, hlo, acc2[bi]);
        acc2[bi] = __builtin_elementwise_fma(whi, hhi, acc2[bi]);
      }
    }
    float bv = btag[kk];
    #pragma unroll
    for (int bi = 0; bi < 8; ++bi)
      feats[(size_t)(bc * 32 + bg * 8 + bi) * 10400 + t * 52 + kk] =
          acc2[bi].x + acc2[bi].y + bv;
  }
}

// ---------------- Viterbi v4 (r11, proven): one WAVE per batch row.
__global__ __launch_bounds__(64) void viterbi_kernel(
    const float* __restrict__ feats, const float* __restrict__ trans,
    const int* __restrict__ blen, float* __restrict__ out) {
  __shared__ float flds[10400];
  __shared__ float pl[56];
  __shared__ unsigned char bp[199 * 52];

  const int b = blockIdx.x;
  const int lane = threadIdx.x;
  const int kk = (lane < 52) ? lane : 0;
  const float* fb = feats + (size_t)b * 10400;
  const int len = blen[b];

  const int nf4 = (len * 52 + 3) >> 2;   // only the live prefix of feats
  for (int i = lane; i < nf4; i += 64)
    *(float4*)&flds[i * 4] = *(const float4*)(fb + i * 4);

  float trc[52];
  #pragma unroll
  for (int j = 0; j < 52; ++j) trc[j] = trans[j * 52 + kk];
  __syncthreads();

  float part = trans[50 * 52 + kk] + flds[kk];   // START row = 50
  if (lane < 52) pl[lane] = part;

  for (int t = 1; t < len; ++t) {   // all iterations unmasked by construction
    const float ftk = flds[t * 52 + kk];
    float pa[52];
    #pragma unroll
    for (int q = 0; q < 13; ++q) {
      float4 v = *(const float4*)&pl[q * 4];
      pa[q * 4 + 0] = v.x; pa[q * 4 + 1] = v.y;
      pa[q * 4 + 2] = v.z; pa[q * 4 + 3] = v.w;
    }
    float mv0 = -1e30f, mv1 = -1e30f, mv2 = -1e30f, mv3 = -1e30f;
    int mj0 = 0, mj1 = 13, mj2 = 26, mj3 = 39;
    #pragma unroll
    for (int q = 0; q < 13; ++q) {
      float c0v = (pa[q] + trc[q]) + ftk;
      if (c0v > mv0) { mv0 = c0v; mj0 = q; }
      float c1v = (pa[13 + q] + trc[13 + q]) + ftk;
      if (c1v > mv1) { mv1 = c1v; mj1 = 13 + q; }
      float c2v = (pa[26 + q] + trc[26 + q]) + ftk;
      if (c2v > mv2) { mv2 = c2v; mj2 = 26 + q; }
      float c3v = (pa[39 + q] + trc[39 + q]) + ftk;
      if (c3v > mv3) { mv3 = c3v; mj3 = 39 + q; }
    }
    float mv = mv0; int mj = mj0;
    if (mv1 > mv) { mv = mv1; mj = mj1; }
    if (mv2 > mv) { mv = mv2; mj = mj2; }
    if (mv3 > mv) { mv = mv3; mj = mj3; }
    if (lane < 52) {
      bp[(t - 1) * 52 + lane] = (unsigned char)mj;
      part = mv; pl[lane] = mv;
    }
  }

  float fin = (lane < 52) ? (part + trans[lane * 52 + 51]) : -1e30f;
  int bi = lane;
  #pragma unroll
  for (int off = 32; off; off >>= 1) {
    float ov = __shfl_down(fin, off);
    int oi = __shfl_down(bi, off);
    if (ov > fin || (ov == fin && oi < bi)) { fin = ov; bi = oi; }
  }
  if (lane == 0) {
    out[b] = fin;
    float* dec = out + 256 + (size_t)b * 200;
    for (int i = len; i < 200; ++i) dec[i] = 0.f;   // masked tail
    int tag = bi;
    dec[len - 1] = (float)tag;                       // == bi (identity beyond)
    for (int i = len - 2; i >= 0; --i) {
      tag = bp[i * 52 + tag];                        // bp[i] real for i<=len-2
      dec[i] = (float)tag;
    }
  }
}

extern "C" void kernel_launch(void* const* d_in, const int* in_sizes, int n_in,
                              void* d_out, int out_size, void* d_ws, size_t ws_size,
                              hipStream_t stream) {
  const int*   bin  = (const int*)d_in[0];
  const int*   bfe  = (const int*)d_in[1];
  const int*   blen = (const int*)d_in[2];
  const float* ctab = (const float*)d_in[5];
  const float* ftab = (const float*)d_in[6];
  const float* wihf = (const float*)d_in[7];
  const float* whhf = (const float*)d_in[8];
  const float* bf   = (const float*)d_in[9];
  const float* wihb = (const float*)d_in[10];
  const float* whhb = (const float*)d_in[11];
  const float* bb   = (const float*)d_in[12];
  const float* wtag = (const float*)d_in[13];
  const float* btag = (const float*)d_in[14];
  const float* trn  = (const float*)d_in[15];

  (void)hipFuncSetAttribute(reinterpret_cast<const void*>(lstm_chunk),
                            hipFuncAttributeMaxDynamicSharedMemorySize,
                            SMEM_BYTES);

  const size_t FIXED_F = 29271040;      // hst+cst+hout+fts+bar
  const size_t EMB_F   = 13107200;      // 200 x 256 x 256
  size_t ws_f = ws_size / sizeof(float);
  int C = 1;
  const int cands[12] = {200, 100, 50, 40, 25, 20, 10, 8, 5, 4, 2, 1};
  for (int u = 0; u < 12; ++u) {
    if (FIXED_F + EMB_F + (size_t)2 * cands[u] * 262144 <= ws_f) {
      C = cands[u]; break;
    }
  }

  float* ws  = (float*)d_ws;
  float* xgf = ws;
  float* xgb = xgf + (size_t)C * 262144;
  float* hst = xgb + (size_t)C * 262144;    // 2 slots x 2 dir x 256 x 256
  float* cst = hst + 262144;
  float* hout = cst + 131072;               // 2 dir x 200 x 256 x 256
  float* fts  = hout + 26214400;
  unsigned* bar = (unsigned*)(fts + 2662400); // 32 groups x stride 32
  float* emb  = (float*)(bar + 1024);       // 200 x 256 x 256
  float* out  = (float*)d_out;

  hipMemsetAsync(hst, 0, (size_t)(262144 + 131072) * sizeof(float), stream);
  hipMemsetAsync(bar, 0, 1024 * sizeof(unsigned), stream);

  emb_kernel<<<dim3(200, 8), 256, 0, stream>>>(bin, bfe, blen, ctab, ftab, emb);

  const int nchunks = 200 / C;
  for (int c = 0; c < nchunks; ++c) {
    xg_gemm<<<dim3(2 * C, 8, 2), 256, 0, stream>>>(
        blen, emb, wihf, bf, wihb, bb, xgf, xgb, c * C);
    lstm_chunk<<<dim3(16, 8, 2), 512, SMEM_BYTES, stream>>>(
        xgf, xgb, whhf, whhb, blen, hst, cst, hout, bar, c * C, C);
  }
  feats_kernel<<<dim3(200, 8), 256, 0, stream>>>(hout, wtag, btag, fts, blen);
  viterbi_kernel<<<256, 64, 0, stream>>>(fts, trn, blen, out);
}